// Round 6
// baseline (472.399 us; speedup 1.0000x reference)
//
#include <hip/hip_runtime.h>
#include <math.h>

#define B 8
#define M 8192
#define N 512
#define R 256
#define EPSF 1e-16f

typedef __attribute__((ext_vector_type(8))) short short8;
typedef __attribute__((ext_vector_type(16))) float f32x16;

__device__ __forceinline__ unsigned short bf16_rtn(float f) {
    unsigned int u = __float_as_uint(f);
    u += 0x7FFFu + ((u >> 16) & 1u);
    return (unsigned short)(u >> 16);
}

// async global->LDS, 16B per lane. LDS dest = wave-uniform base + lane*16.
__device__ __forceinline__ void gll16(const unsigned short* g, unsigned short* l) {
    __builtin_amdgcn_global_load_lds(
        (const __attribute__((address_space(1))) unsigned int*)g,
        (__attribute__((address_space(3))) unsigned int*)l, 16, 0, 0);
}

// ---------------------------------------------------------------------------
// Kc: gather centers x[b, inds, :] -> c_hi/c_lo (split bf16) + exact fp32 v2.
// ---------------------------------------------------------------------------
__global__ __launch_bounds__(256) void ekm_kc(
    const float* __restrict__ x, const int* __restrict__ inds,
    unsigned short* __restrict__ c_hi, unsigned short* __restrict__ c_lo,
    float* __restrict__ v2g)
{
    const int t = threadIdx.x, b = blockIdx.y;
    const int r = blockIdx.x * 16 + (t >> 4);
    const int seg = (t & 15) * 32;
    const float* src = x + ((size_t)b * M + inds[r]) * N + seg;
    unsigned short* hd = c_hi + ((size_t)b * R + r) * 512 + seg;
    unsigned short* ld = c_lo + ((size_t)b * R + r) * 512 + seg;
    float vp = 0.f;
#pragma unroll
    for (int c = 0; c < 4; ++c) {
        float4 f0 = *(const float4*)(src + c * 8);
        float4 f1 = *(const float4*)(src + c * 8 + 4);
        float av[8] = {f0.x, f0.y, f0.z, f0.w, f1.x, f1.y, f1.z, f1.w};
        unsigned ph[4], pl[4];
#pragma unroll
        for (int j = 0; j < 4; ++j) {
            vp += av[2*j] * av[2*j] + av[2*j+1] * av[2*j+1];
            unsigned short h0 = bf16_rtn(av[2*j]), h1 = bf16_rtn(av[2*j+1]);
            float r0 = av[2*j]   - __uint_as_float((unsigned)h0 << 16);
            float r1 = av[2*j+1] - __uint_as_float((unsigned)h1 << 16);
            ph[j] = (unsigned)h0 | ((unsigned)h1 << 16);
            pl[j] = (unsigned)bf16_rtn(r0) | ((unsigned)bf16_rtn(r1) << 16);
        }
        *(uint4*)(hd + c * 8) = make_uint4(ph[0], ph[1], ph[2], ph[3]);
        *(uint4*)(ld + c * 8) = make_uint4(pl[0], pl[1], pl[2], pl[3]);
    }
    vp += __shfl_xor(vp, 1); vp += __shfl_xor(vp, 2);
    vp += __shfl_xor(vp, 4); vp += __shfl_xor(vp, 8);
    if ((t & 15) == 0) v2g[b * R + r] = vp;
}

// ---------------------------------------------------------------------------
// T: x fp32 [b][m][n] -> xT bf16 [b][n][m]. LDS transpose, pad 130 (2-way free).
// grid (M/64, N/128, B), block 256.
// ---------------------------------------------------------------------------
__global__ __launch_bounds__(256) void ekm_t(
    const float* __restrict__ x, unsigned short* __restrict__ xT)
{
    __shared__ unsigned short S[64 * 130];
    const int t = threadIdx.x;
    const int m0 = blockIdx.x * 64, n0 = blockIdx.y * 128, b = blockIdx.z;
#pragma unroll
    for (int it = 0; it < 8; ++it) {
        int idx = it * 256 + t;
        int m = idx >> 5, c4 = idx & 31;
        float4 v = *(const float4*)(x + ((size_t)b * M + m0 + m) * N + n0 + c4 * 4);
        uint2 p;
        p.x = (unsigned)bf16_rtn(v.x) | ((unsigned)bf16_rtn(v.y) << 16);
        p.y = (unsigned)bf16_rtn(v.z) | ((unsigned)bf16_rtn(v.w) << 16);
        *(uint2*)&S[m * 130 + c4 * 4] = p;
    }
    __syncthreads();
#pragma unroll
    for (int it = 0; it < 4; ++it) {
        int idx = it * 256 + t;
        int n = idx >> 3, mc = (idx & 7) * 8;
        unsigned q[4];
#pragma unroll
        for (int j = 0; j < 4; ++j)
            q[j] = (unsigned)S[(mc + 2*j) * 130 + n] | ((unsigned)S[(mc + 2*j + 1) * 130 + n] << 16);
        *(uint4*)(xT + ((size_t)b * N + n0 + n) * M + m0 + mc) = make_uint4(q[0], q[1], q[2], q[3]);
    }
}

// ---------------------------------------------------------------------------
// K1: split-bf16 32x32x16 MFMA distances + fused softmax.
// A: fp32 inline-converted, padded LDS (shared). B: direct global->VGPR
// (wave-private rows of L2-hot c_hi/c_lo) -- no gll, lgkm-only barriers.
// ---------------------------------------------------------------------------
__global__ __launch_bounds__(256, 3) void ekm_k1(
    const float* __restrict__ x, const float* __restrict__ alpha_p,
    const unsigned short* __restrict__ c_hi, const unsigned short* __restrict__ c_lo,
    const float* __restrict__ v2g, float* __restrict__ u_out,
    unsigned short* __restrict__ uT, float* __restrict__ colsum)
{
    __shared__ unsigned short Ah[64 * 40], Al[64 * 40];
    __shared__ float x2s[64];
    __shared__ float redm[4][64], reds[4][64];

    const int t = threadIdx.x;
    const int b = blockIdx.y;
    const int m0 = blockIdx.x * 64;
    const int w = t >> 6, l = t & 63, col = l & 31, h5 = l >> 5;
    const int arow = t >> 2, kch = t & 3;

    const float* ax = x + ((size_t)b * M + m0 + arow) * N + kch * 8;
    // wave-private B row base (this lane's column of the r-tile)
    const size_t rowb = (size_t)(b * R + w * 64 + col) * 512 + h5 * 8;
    const unsigned short* bh_p = c_hi + rowb;
    const unsigned short* bl_p = c_lo + rowb;

    f32x16 acc[2][2];
    acc[0][0] = (f32x16)0.f; acc[0][1] = (f32x16)0.f;
    acc[1][0] = (f32x16)0.f; acc[1][1] = (f32x16)0.f;

    float x2p = 0.f;
    float4 a0 = *(const float4*)(ax);
    float4 a1 = *(const float4*)(ax + 4);

    for (int k0 = 0; k0 < N; k0 += 32) {
        // convert prefetched A (fp32 -> hi/lo bf16), exact x2 accumulation
        x2p += a0.x*a0.x + a0.y*a0.y + a0.z*a0.z + a0.w*a0.w
             + a1.x*a1.x + a1.y*a1.y + a1.z*a1.z + a1.w*a1.w;
        float av[8] = {a0.x, a0.y, a0.z, a0.w, a1.x, a1.y, a1.z, a1.w};
        unsigned ph[4], pl[4];
#pragma unroll
        for (int j = 0; j < 4; ++j) {
            unsigned short h0 = bf16_rtn(av[2*j]), h1 = bf16_rtn(av[2*j+1]);
            float r0 = av[2*j]   - __uint_as_float((unsigned)h0 << 16);
            float r1 = av[2*j+1] - __uint_as_float((unsigned)h1 << 16);
            ph[j] = (unsigned)h0 | ((unsigned)h1 << 16);
            pl[j] = (unsigned)bf16_rtn(r0) | ((unsigned)bf16_rtn(r1) << 16);
        }
        __syncthreads();   // previous A-tile fully consumed (lgkm only)
        *(uint4*)&Ah[arow * 40 + kch * 8] = make_uint4(ph[0], ph[1], ph[2], ph[3]);
        *(uint4*)&Al[arow * 40 + kch * 8] = make_uint4(pl[0], pl[1], pl[2], pl[3]);
        __syncthreads();

        // prefetch next A after the barrier (hidden behind MFMA section)
        if (k0 + 32 < N) {
            a0 = *(const float4*)(ax + k0 + 32);
            a1 = *(const float4*)(ax + k0 + 36);
        }

        // B fragments: direct global->VGPR (L2-hot, lines exactly tiled)
        short8 bh[2][2], bl[2][2];
#pragma unroll
        for (int tr = 0; tr < 2; ++tr)
#pragma unroll
            for (int half = 0; half < 2; ++half) {
                bh[tr][half] = *(const short8*)(bh_p + tr * 32 * 512 + k0 + half * 16);
                bl[tr][half] = *(const short8*)(bl_p + tr * 32 * 512 + k0 + half * 16);
            }

#pragma unroll
        for (int half = 0; half < 2; ++half) {
            short8 ah[2], al2[2];
#pragma unroll
            for (int tm = 0; tm < 2; ++tm) {
                ah[tm]  = *(const short8*)&Ah[(tm*32 + col) * 40 + half*16 + h5*8];
                al2[tm] = *(const short8*)&Al[(tm*32 + col) * 40 + half*16 + h5*8];
            }
            // pass-major order: same-acc dependency distance = 4
#pragma unroll
            for (int tm = 0; tm < 2; ++tm)
#pragma unroll
            for (int tr = 0; tr < 2; ++tr)
                acc[tm][tr] = __builtin_amdgcn_mfma_f32_32x32x16_bf16(ah[tm], bh[tr][half], acc[tm][tr], 0, 0, 0);
#pragma unroll
            for (int tm = 0; tm < 2; ++tm)
#pragma unroll
            for (int tr = 0; tr < 2; ++tr)
                acc[tm][tr] = __builtin_amdgcn_mfma_f32_32x32x16_bf16(ah[tm], bl[tr][half], acc[tm][tr], 0, 0, 0);
#pragma unroll
            for (int tm = 0; tm < 2; ++tm)
#pragma unroll
            for (int tr = 0; tr < 2; ++tr)
                acc[tm][tr] = __builtin_amdgcn_mfma_f32_32x32x16_bf16(al2[tm], bh[tr][half], acc[tm][tr], 0, 0, 0);
        }
    }

    // ---- epilogue ----
    x2p += __shfl_xor(x2p, 1);
    x2p += __shfl_xor(x2p, 2);
    if (kch == 0) x2s[arow] = x2p;
    __syncthreads();

    const float ia = 1.4426950408889634f / alpha_p[0];  // log2(e)/alpha
    float v2c[2];
#pragma unroll
    for (int tr = 0; tr < 2; ++tr)
        v2c[tr] = v2g[b * R + w * 64 + tr * 32 + col];

    // d = relu(x2 - 2xv + v2); wave-local row min
#pragma unroll
    for (int tm = 0; tm < 2; ++tm)
#pragma unroll
    for (int reg = 0; reg < 16; ++reg) {
        int rowl = (reg & 3) + 8 * (reg >> 2) + 4 * h5;
        float x2v = x2s[tm * 32 + rowl];
        float mn;
#pragma unroll
        for (int tr = 0; tr < 2; ++tr) {
            float d = x2v - 2.f * acc[tm][tr][reg] + v2c[tr];
            d = fmaxf(d, 0.f);
            acc[tm][tr][reg] = d;
            mn = (tr == 0) ? d : fminf(mn, d);
        }
        mn = fminf(mn, __shfl_xor(mn, 1));
        mn = fminf(mn, __shfl_xor(mn, 2));
        mn = fminf(mn, __shfl_xor(mn, 4));
        mn = fminf(mn, __shfl_xor(mn, 8));
        mn = fminf(mn, __shfl_xor(mn, 16));
        if (col == 0) redm[w][tm * 32 + rowl] = mn;
    }
    __syncthreads();

    // exp + row sum
#pragma unroll
    for (int tm = 0; tm < 2; ++tm)
#pragma unroll
    for (int reg = 0; reg < 16; ++reg) {
        int m = tm * 32 + (reg & 3) + 8 * (reg >> 2) + 4 * h5;
        float mn = fminf(fminf(redm[0][m], redm[1][m]), fminf(redm[2][m], redm[3][m]));
        float s = 0.f;
#pragma unroll
        for (int tr = 0; tr < 2; ++tr) {
            float e = exp2f((mn - acc[tm][tr][reg]) * ia);
            acc[tm][tr][reg] = e;
            s += e;
        }
        s += __shfl_xor(s, 1); s += __shfl_xor(s, 2); s += __shfl_xor(s, 4);
        s += __shfl_xor(s, 8); s += __shfl_xor(s, 16);
        if (col == 0) reds[w][m] = s;
    }
    __syncthreads();

    // normalize, write u (fp32), accumulate colsum, pack uT (bf16)
    float* ub = u_out + ((size_t)b * M + m0) * R + w * 64;
    float cs[2] = {0.f, 0.f};
#pragma unroll
    for (int tm = 0; tm < 2; ++tm)
#pragma unroll
    for (int reg = 0; reg < 16; ++reg) {
        int rowl = (reg & 3) + 8 * (reg >> 2) + 4 * h5;
        int m = tm * 32 + rowl;
        float inv = 1.f / (reds[0][m] + reds[1][m] + reds[2][m] + reds[3][m]);
#pragma unroll
        for (int tr = 0; tr < 2; ++tr) {
            float uu = acc[tm][tr][reg] * inv;
            acc[tm][tr][reg] = uu;
            ub[(size_t)m * R + tr * 32 + col] = uu;
            cs[tr] += uu;
        }
    }
    unsigned short* uTb = uT + ((size_t)b * R + w * 64) * M + m0;
#pragma unroll
    for (int tm = 0; tm < 2; ++tm)
#pragma unroll
    for (int tr = 0; tr < 2; ++tr)
#pragma unroll
    for (int rq = 0; rq < 4; ++rq) {
        uint2 p;
        p.x = (unsigned)bf16_rtn(acc[tm][tr][rq*4+0]) | ((unsigned)bf16_rtn(acc[tm][tr][rq*4+1]) << 16);
        p.y = (unsigned)bf16_rtn(acc[tm][tr][rq*4+2]) | ((unsigned)bf16_rtn(acc[tm][tr][rq*4+3]) << 16);
        *(uint2*)(uTb + (size_t)(tr*32 + col) * M + tm*32 + 8*rq + 4*h5) = p;
    }
    cs[0] += __shfl_xor(cs[0], 32);
    cs[1] += __shfl_xor(cs[1], 32);
    if (h5 == 0) {
        atomicAdd(&colsum[b * R + w * 64 + col], cs[0]);
        atomicAdd(&colsum[b * R + w * 64 + 32 + col], cs[1]);
    }
}

// ---------------------------------------------------------------------------
// K2: v[b][n][r] = (sum_m xT[n][m]*uT[r][m]) / (colsum[r]+eps).
// 64n x 64r tile, full K=8192, BK=128. A via swizzled gll-LDS (shared),
// B direct global->VGPR (wave-private rows). No partials, no atomics.
// grid (N/64, R/64, B) = 256 blocks, 4 waves (wn=w>>1, wr=w&1).
// ---------------------------------------------------------------------------
__global__ __launch_bounds__(256, 4) void ekm_k2(
    const unsigned short* __restrict__ xT, const unsigned short* __restrict__ uT,
    const float* __restrict__ colsum, float* __restrict__ v_out)
{
    __shared__ unsigned short XS[64 * 128];   // [n row][swizzled 16B chunks]
    const int t = threadIdx.x;
    const int n0 = blockIdx.x * 64, r0 = blockIdx.y * 64, b = blockIdx.z;
    const int w = t >> 6, l = t & 63, col = l & 31, h5 = l >> 5;
    const int wn = w >> 1, wr = w & 1;

    // gll source: row n0 + i*16 + (t>>4), chunk (t&15)^((t>>4)&15)
    const int schunk = (t & 15) ^ ((t >> 4) & 15);
    const unsigned short* xs = xT + ((size_t)b * N + n0 + (t >> 4)) * M + schunk * 8;
    const unsigned short* ub = uT + ((size_t)(b * R + r0 + wr * 32 + col)) * M + h5 * 8;

    f32x16 acc0 = (f32x16)0.f, acc1 = (f32x16)0.f;

    for (int k0 = 0; k0 < M; k0 += 128) {
        __syncthreads();
#pragma unroll
        for (int i = 0; i < 4; ++i)
            gll16(xs + (size_t)i * 16 * M + k0, XS + i * 2048 + t * 8);
        __syncthreads();

        short8 bfrag[8];
#pragma unroll
        for (int g = 0; g < 8; ++g)
            bfrag[g] = *(const short8*)(ub + k0 + g * 16);

#pragma unroll
        for (int g = 0; g < 8; ++g) {
            const int pc = (2 * g + h5) ^ (col & 15);
            short8 af = *(const short8*)&XS[(wn * 32 + col) * 128 + pc * 8];
            if (g & 1)
                acc1 = __builtin_amdgcn_mfma_f32_32x32x16_bf16(af, bfrag[g], acc1, 0, 0, 0);
            else
                acc0 = __builtin_amdgcn_mfma_f32_32x32x16_bf16(af, bfrag[g], acc0, 0, 0, 0);
        }
    }

    const float inv = 1.f / (colsum[b * R + r0 + wr * 32 + col] + EPSF);
#pragma unroll
    for (int reg = 0; reg < 16; ++reg) {
        int n = n0 + wn * 32 + (reg & 3) + 8 * (reg >> 2) + 4 * h5;
        v_out[((size_t)b * N + n) * R + r0 + wr * 32 + col] = (acc0[reg] + acc1[reg]) * inv;
    }
}

extern "C" void kernel_launch(void* const* d_in, const int* in_sizes, int n_in,
                              void* d_out, int out_size, void* d_ws, size_t ws_size,
                              hipStream_t stream) {
    const float* x     = (const float*)d_in[0];
    const float* alpha = (const float*)d_in[1];
    const int*   inds  = (const int*)d_in[2];

    float* u_out = (float*)d_out;                    // B*M*R fp32
    float* v_out = u_out + (size_t)B * M * R;        // B*N*R fp32

    char* ws = (char*)d_ws;
    const size_t CH = (size_t)B * R * 512 * 2;       // 2 MB each c_hi/c_lo
    unsigned short* c_hi   = (unsigned short*)ws;
    unsigned short* c_lo   = (unsigned short*)(ws + CH);
    float*          v2g    = (float*)(ws + 2 * CH);
    float*          colsum = (float*)(ws + 2 * CH + (size_t)B * R * 4);
    char* p = ws + 2 * CH + 2 * (size_t)B * R * 4;
    unsigned short* xT = (unsigned short*)p;          p += (size_t)B * N * M * 2;  // 67 MB
    unsigned short* uT = (unsigned short*)p;                                       // 33.5 MB

    hipMemsetAsync(colsum, 0, (size_t)B * R * sizeof(float), stream);

    ekm_kc<<<dim3(16, B), 256, 0, stream>>>(x, inds, c_hi, c_lo, v2g);
    ekm_k1<<<dim3(M / 64, B), 256, 0, stream>>>(x, alpha, c_hi, c_lo, v2g,
                                                u_out, uT, colsum);
    ekm_t<<<dim3(M / 64, N / 128, B), 256, 0, stream>>>(x, xT);
    ekm_k2<<<dim3(N / 64, R / 64, B), 256, 0, stream>>>(xT, uT, colsum, v_out);
}